// Round 4
// baseline (440.366 us; speedup 1.0000x reference)
//
#include <hip/hip_runtime.h>
#include <hip/hip_bf16.h>
#include <cstdint>

#define N_NODES 100000
#define BQ      20000
#define KN      32
#define DIM     256
#define NEGV    -1000000.0f

typedef float          f32x4 __attribute__((ext_vector_type(4)));
typedef __bf16         bfx8  __attribute__((ext_vector_type(8)));
typedef unsigned short u16x8 __attribute__((ext_vector_type(8)));
typedef unsigned short u16x4 __attribute__((ext_vector_type(4)));

static __device__ __forceinline__ unsigned short f2bf(float f) {
    unsigned u = __builtin_bit_cast(unsigned, f);
    u += 0x7FFFu + ((u >> 16) & 1u);   // round-to-nearest-even
    return (unsigned short)(u >> 16);
}

// ---------------------------------------------------------------------------
// Kernel 1: proj = leaky_relu(word_vec @ W1^T)  [N,256] fp32 out
// 128x128 tile per block, K=256 staged as two 128-halves in bf16 LDS
// (XOR-swizzled), mfma_f32_16x16x32_bf16, 4 waves each owning a 64x64 quadrant.
// ---------------------------------------------------------------------------
__global__ __launch_bounds__(256) void proj_gemm(const float* __restrict__ A,
                                                 const float* __restrict__ W,
                                                 float* __restrict__ out) {
    __shared__ unsigned short As[128 * 128];  // 32 KiB bf16, swizzled
    __shared__ unsigned short Bs[128 * 128];  // 32 KiB

    const int tile = blockIdx.x;
    const int mt = tile >> 1, nt = tile & 1;
    const int m0 = mt * 128, n0 = nt * 128;
    const int t = threadIdx.x;
    const int lane = t & 63;
    const int w = t >> 6;
    const int wm = (w >> 1) * 64;   // wave's M offset in tile
    const int wn = (w & 1) * 64;    // wave's N offset in tile

    f32x4 acc[4][4];
#pragma unroll
    for (int i = 0; i < 4; ++i)
#pragma unroll
        for (int j = 0; j < 4; ++j) acc[i][j] = f32x4{0.f, 0.f, 0.f, 0.f};

    const int r_ = t >> 5;          // 0..7 (row within 8-row staging stripe)
    const int c_ = (t & 31) * 4;    // f32 col 0..124

#pragma unroll 1
    for (int half = 0; half < 2; ++half) {
        const int k0 = half * 128;

        // ---- stage A (word_vec rows) and B (W1 rows) halves, fp32->bf16 ----
#pragma unroll
        for (int it = 0; it < 16; ++it) {
            const int row = it * 8 + r_;
            // A
            {
                const int gr = m0 + row;
                f32x4 v = f32x4{0.f, 0.f, 0.f, 0.f};
                if (gr < N_NODES) v = *(const f32x4*)&A[(size_t)gr * 256 + k0 + c_];
                u16x4 h = {f2bf(v[0]), f2bf(v[1]), f2bf(v[2]), f2bf(v[3])};
                int byte = row * 256 + c_ * 2;
                byte ^= (row & 7) << 4;
                *reinterpret_cast<u16x4*>(reinterpret_cast<char*>(As) + byte) = h;
            }
            // B (no guard: n0+row <= 255)
            {
                const int gr = n0 + row;
                f32x4 v = *(const f32x4*)&W[(size_t)gr * 256 + k0 + c_];
                u16x4 h = {f2bf(v[0]), f2bf(v[1]), f2bf(v[2]), f2bf(v[3])};
                int byte = row * 256 + c_ * 2;
                byte ^= (row & 7) << 4;
                *reinterpret_cast<u16x4*>(reinterpret_cast<char*>(Bs) + byte) = h;
            }
        }
        __syncthreads();

        // ---- MFMA over this K-half: 4 steps of K=32 ----
#pragma unroll
        for (int ks = 0; ks < 4; ++ks) {
            const int colb = (ks * 32 + ((lane >> 4) * 8)) * 2;  // byte col in LDS row
            bfx8 af[4], bfv[4];
#pragma unroll
            for (int mi = 0; mi < 4; ++mi) {
                const int row = wm + mi * 16 + (lane & 15);
                const int byte = row * 256 + (colb ^ ((row & 7) << 4));
                af[mi] = __builtin_bit_cast(
                    bfx8, *reinterpret_cast<const u16x8*>(reinterpret_cast<const char*>(As) + byte));
            }
#pragma unroll
            for (int ni = 0; ni < 4; ++ni) {
                const int row = wn + ni * 16 + (lane & 15);
                const int byte = row * 256 + (colb ^ ((row & 7) << 4));
                bfv[ni] = __builtin_bit_cast(
                    bfx8, *reinterpret_cast<const u16x8*>(reinterpret_cast<const char*>(Bs) + byte));
            }
#pragma unroll
            for (int mi = 0; mi < 4; ++mi)
#pragma unroll
                for (int ni = 0; ni < 4; ++ni)
                    acc[mi][ni] = __builtin_amdgcn_mfma_f32_16x16x32_bf16(af[mi], bfv[ni],
                                                                          acc[mi][ni], 0, 0, 0);
        }
        __syncthreads();
    }

    // ---- epilogue: leaky_relu + store ----
    const int cr = (lane >> 4) * 4;  // fragment row base
    const int cc = lane & 15;        // fragment col
#pragma unroll
    for (int mi = 0; mi < 4; ++mi) {
#pragma unroll
        for (int r = 0; r < 4; ++r) {
            const int grow = m0 + wm + mi * 16 + cr + r;
            if (grow < N_NODES) {
#pragma unroll
                for (int ni = 0; ni < 4; ++ni) {
                    float v = acc[mi][ni][r];
                    v = v > 0.f ? v : 0.2f * v;
                    out[(size_t)grow * 256 + n0 + wn + ni * 16 + cc] = v;
                }
            }
        }
    }
}

// ---------------------------------------------------------------------------
// Kernel 2: per-b scores + masked softmaxes + weighted aggregation of proj rows
// one block (256 thr / 4 waves) per b; agg -> workspace
// ---------------------------------------------------------------------------
__global__ __launch_bounds__(256) void att_agg(const float* __restrict__ wv,
                                               const float* __restrict__ Waux,
                                               const float* __restrict__ aux,
                                               const int* __restrict__ src_idx,
                                               const int* __restrict__ nidx,
                                               const int* __restrict__ smask,
                                               const float* __restrict__ proj,
                                               float* __restrict__ agg) {
    __shared__ float qsh[256];
    __shared__ int   nsh[32];
    __shared__ int   msh[32];
    __shared__ float sc[32];
    __shared__ float sa[32];
    __shared__ float wsh[32];

    const int b = blockIdx.x;
    const int t = threadIdx.x;
    const int lane = t & 63;
    const int w = t >> 6;
    const int src = src_idx[b];

    if (t < 32) {
        nsh[t] = nidx[b * KN + t];
        msh[t] = smask[b * KN + t];
        f32x4 a4 = *(const f32x4*)&aux[((size_t)b * KN + t) * 4];
        const float x = a4[0] * Waux[0] + a4[1] * Waux[1] + a4[2] * Waux[2] + a4[3] * Waux[3];
        sa[t] = 1.f / (1.f + expf(-x));
    }
    if (t < 64) {
        *(f32x4*)&qsh[t * 4] = *(const f32x4*)&wv[(size_t)src * 256 + t * 4];
    }
    __syncthreads();

    // scores: wave w handles neighbors w*8 .. w*8+7; full-wave dot of length 256
    const f32x4 q4 = *(const f32x4*)&qsh[lane * 4];
#pragma unroll
    for (int i = 0; i < 8; ++i) {
        const int j = w * 8 + i;
        const int nj = nsh[j];
        const f32x4 k4 = *(const f32x4*)&wv[(size_t)nj * 256 + lane * 4];
        float p = q4[0] * k4[0] + q4[1] * k4[1] + q4[2] * k4[2] + q4[3] * k4[3];
#pragma unroll
        for (int o = 32; o > 0; o >>= 1) p += __shfl_xor(p, o);
        if (lane == 0) sc[j] = 5.f * p;
    }
    __syncthreads();

    // masked softmaxes over K=32 (lanes 0..31 of wave 0)
    if (t < 32) {
        const bool mk = (msh[t] == 1);
        const float s1 = mk ? sc[t] : NEGV;
        const float s2 = mk ? sa[t] : NEGV;
        float m1 = s1, m2 = s2;
#pragma unroll
        for (int o = 16; o > 0; o >>= 1) {
            m1 = fmaxf(m1, __shfl_xor(m1, o));
            m2 = fmaxf(m2, __shfl_xor(m2, o));
        }
        const float e1 = expf(s1 - m1), e2 = expf(s2 - m2);
        float z1 = e1, z2 = e2;
#pragma unroll
        for (int o = 16; o > 0; o >>= 1) {
            z1 += __shfl_xor(z1, o);
            z2 += __shfl_xor(z2, o);
        }
        wsh[t] = 0.5f * (e1 / z1 + e2 / z2);
    }
    __syncthreads();

    // aggregation: thread t owns output dim t
    float accv = 0.f;
#pragma unroll
    for (int k = 0; k < KN; ++k) {
        accv += wsh[k] * proj[(size_t)nsh[k] * 256 + t];
    }
    agg[(size_t)b * 256 + t] = accv;
}

// ---------------------------------------------------------------------------
// Kernel 3: scatter agg rows into out at src_idx
// ---------------------------------------------------------------------------
__global__ __launch_bounds__(256) void scatter_agg(const int* __restrict__ src_idx,
                                                   const float* __restrict__ agg,
                                                   float* __restrict__ out) {
    const int b = blockIdx.x;
    const int t = threadIdx.x;
    out[(size_t)src_idx[b] * 256 + t] = agg[(size_t)b * 256 + t];
}

extern "C" void kernel_launch(void* const* d_in, const int* in_sizes, int n_in,
                              void* d_out, int out_size, void* d_ws, size_t ws_size,
                              hipStream_t stream) {
    const float* wv   = (const float*)d_in[0];  // word_vec [N,256]
    const float* W1   = (const float*)d_in[1];  // [256,256]
    const float* Waux = (const float*)d_in[2];  // [1,4]
    const float* aux  = (const float*)d_in[3];  // [B,K,4]
    const int*   src  = (const int*)d_in[4];    // [B]
    const int*   nidx = (const int*)d_in[5];    // [B,K]
    const int*   smk  = (const int*)d_in[6];    // [B,K]
    float* out = (float*)d_out;                 // [N,256]
    float* agg = (float*)d_ws;                  // [B,256] scratch (20.48 MB)

    const int mtiles = (N_NODES + 127) / 128;   // 782
    proj_gemm<<<dim3(mtiles * 2), dim3(256), 0, stream>>>(wv, W1, out);
    att_agg<<<dim3(BQ), dim3(256), 0, stream>>>(wv, Waux, aux, src, nidx, smk, out, agg);
    scatter_agg<<<dim3(BQ), dim3(256), 0, stream>>>(src, agg, out);
}